// Round 13
// baseline (302.453 us; speedup 1.0000x reference)
//
#include <hip/hip_runtime.h>
#include <hip/hip_bf16.h>
#include <stdint.h>

#define BATCH 8
#define SEQ   2048
#define DIM   1024

typedef unsigned short u16;
typedef __attribute__((ext_vector_type(8))) short short8;
typedef __attribute__((ext_vector_type(4))) float f32x4;
typedef __attribute__((ext_vector_type(16))) float f32x16;
typedef __attribute__((ext_vector_type(4))) unsigned short us4;

__device__ __forceinline__ u16 f2bf(float x){
  union { float f; uint32_t u; } c; c.f = x;
  uint32_t u = c.u;
  uint32_t r = u + 0x7fffu + ((u >> 16) & 1u);
  return (u16)(r >> 16);
}
__device__ __forceinline__ float bf2f(u16 s){
  union { uint32_t u; float f; } c; c.u = ((uint32_t)s) << 16;
  return c.f;
}

__device__ __forceinline__ void gload16(const void* g, void* l){
  __builtin_amdgcn_global_load_lds(
      (const __attribute__((address_space(1))) void*)g,
      (__attribute__((address_space(3))) void*)l, 16, 0, 0);
}

// ---------- split fp32 [R][1024] -> u16 [R][2048] rows packed [hi|lo] ----------
__global__ __launch_bounds__(256) void k_split(const float* __restrict__ src,
                                               u16* __restrict__ dst, int nchunk){
  for (int i = blockIdx.x*blockDim.x + threadIdx.x; i < nchunk; i += gridDim.x*blockDim.x){
    int r = i >> 8;
    int c = (i & 255) << 2;
    f32x4 v = *(const f32x4*)(src + (size_t)r*DIM + c);
    us4 h, l;
    #pragma unroll
    for (int j = 0; j < 4; j++){
      u16 hh = f2bf(v[j]);
      h[j] = hh;
      l[j] = f2bf(v[j] - bf2f(hh));
    }
    u16* d = dst + (size_t)r*(2*DIM) + c;
    *(us4*)d         = h;
    *(us4*)(d + DIM) = l;
  }
}

// ---------- transpose + split (K and V in one launch): z<8 -> K->Kt, z>=8 -> V->Vt ----------
__global__ __launch_bounds__(256) void k_convert_kv(const float* __restrict__ K,
                                                    const float* __restrict__ V,
                                                    u16* __restrict__ Kt,
                                                    u16* __restrict__ Vt){
  __shared__ float tile[64][65];
  int z = blockIdx.z;
  const float* Src = (z < 8 ? K : V);
  u16* Dst = (z < 8 ? Kt : Vt);
  int zb = z & 7;
  const float* Vb = Src + (size_t)zb * SEQ * DIM;
  u16* Vtb = Dst + (size_t)zb * DIM * (2*SEQ);
  int s0 = blockIdx.x * 64, d0 = blockIdx.y * 64;
  int t = threadIdx.x;
  int rs = t >> 4;
  int cd = (t & 15) * 4;
  #pragma unroll
  for (int i = 0; i < 4; i++){
    int s = rs + i*16;
    f32x4 v = *(const f32x4*)(Vb + (size_t)(s0 + s)*DIM + d0 + cd);
    tile[s][cd+0] = v[0]; tile[s][cd+1] = v[1];
    tile[s][cd+2] = v[2]; tile[s][cd+3] = v[3];
  }
  __syncthreads();
  int dl = t >> 4;
  int sl = (t & 15) * 4;
  #pragma unroll
  for (int i = 0; i < 4; i++){
    int d = dl + i*16;
    us4 h, l;
    #pragma unroll
    for (int j = 0; j < 4; j++){
      float x = tile[sl+j][d];
      u16 hh = f2bf(x);
      h[j] = hh;
      l[j] = f2bf(x - bf2f(hh));
    }
    size_t off = (size_t)(d0 + d) * (2*SEQ) + s0 + sl;
    *(us4*)(Vtb + off)       = h;
    *(us4*)(Vtb + off + SEQ) = l;
  }
}

// ---------- 256x256 8-wave GEMM, hi/lo mfma3, 32x32x16 MFMA, dbuf prefetch-1 ----------
// A: [M][2*KROW] u16 [hi|lo]; B: [N][2*KROW]. Wave tile 128x64 (4x2 of 32x32).
// LDS [2 buf][Ah,Al,Bh,Bl][256x32] = 128 KB. R8-verified 2-barrier loop + vmcnt(8).
// 32x32x16 layouts: A/B lane: row=lane&31, k-chunk (lane>>5)*8;
// C/D: col=lane&31, row=(reg&3)+8*(reg>>2)+4*(lane>>5)  [m74/m101 HW-verified].
// SPLITK: z=(kh<<3)|zb contracts K-half kh. fp32 C out, ld=1024.
template<int KROW, int SPLITK, int TX, int TY>
__global__ __launch_bounds__(512,1) void k32(const u16* __restrict__ A,
                                             const u16* __restrict__ B,
                                             float* __restrict__ C,
                                             size_t aStride, size_t bStride, size_t cStride){
  constexpr int LA = 2*KROW;
  constexpr int NT = (SPLITK ? 1024 : KROW) / 32;
  __shared__ __align__(16) u16 lds[2][4][256*32];

  int xcd = blockIdx.x & 7;
  int idx = blockIdx.x >> 3;
  int nPerX = gridDim.x >> 3;
  int gid = xcd * nPerX + idx;
  constexpr int TPZ = TX*TY;
  int z  = gid / TPZ;
  int rm = gid % TPZ;
  int bx = rm % TX;
  int by = rm / TX;
  int zb = SPLITK ? (z & 7) : z;
  int kh = SPLITK ? (z >> 3) : 0;

  const u16* Ab = A + (size_t)zb * aStride + (size_t)kh * 1024;
  const u16* Bb = B + (size_t)zb * bStride + (size_t)kh * 1024;
  float* Cb = C + (size_t)z * cStride;

  int t0 = threadIdx.x, lane = t0 & 63, wv = t0 >> 6;
  int wm = (wv >> 2) * 128, wn = (wv & 3) * 64;
  int l31 = lane & 31;
  int khg = lane >> 5;                  // k-chunk selector within fragment
  int rdX = (lane >> 1) & 3;            // == (row>>1)&3 for our row groups
  int rs0 = ((0 + khg) ^ rdX) * 8;      // ks=0 slots {0,1}
  int rs1 = ((2 + khg) ^ rdX) * 8;      // ks=1 slots {2,3}
  int srow = lane >> 2;
  int srcSlot = ((lane & 3) ^ ((lane >> 3) & 3)) * 8;

  const u16* aB = Ab + (size_t)bx*256*LA + srcSlot;
  const u16* bB = Bb + (size_t)by*256*LA + srcSlot;

  f32x16 acc[4][2] = {};
  short8 aH[4], aL[4], bH[2], bL[2];

  #define STAGE(buf, t32)                                                     \
    { _Pragma("unroll")                                                       \
      for (int hf = 0; hf < 2; hf++){                                         \
        size_t ro = (size_t)(wv*16 + hf*128 + srow) * LA + (size_t)(t32)*32;  \
        const u16* ga = aB + ro;                                              \
        const u16* gb = bB + ro;                                              \
        int lo = wv*512 + hf*4096;                                            \
        gload16(ga,        &lds[buf][0][lo]);                                 \
        gload16(ga + KROW, &lds[buf][1][lo]);                                 \
        gload16(gb,        &lds[buf][2][lo]);                                 \
        gload16(gb + KROW, &lds[buf][3][lo]);                                 \
      } }

  #define KSTEP(buf, rs)                                                      \
    { _Pragma("unroll")                                                       \
      for (int f = 0; f < 4; f++){                                            \
        int ra = (wm + f*32 + l31)*32 + (rs);                                 \
        aH[f] = *(const short8*)&lds[buf][0][ra];                             \
        aL[f] = *(const short8*)&lds[buf][1][ra];                             \
      }                                                                       \
      _Pragma("unroll")                                                       \
      for (int g = 0; g < 2; g++){                                            \
        int rb = (wn + g*32 + l31)*32 + (rs);                                 \
        bH[g] = *(const short8*)&lds[buf][2][rb];                             \
        bL[g] = *(const short8*)&lds[buf][3][rb];                             \
      }                                                                       \
      __builtin_amdgcn_s_setprio(1);                                          \
      _Pragma("unroll")                                                       \
      for (int f = 0; f < 4; f++){                                            \
        _Pragma("unroll")                                                     \
        for (int g = 0; g < 2; g++){                                          \
          f32x16 c0 = acc[f][g];                                              \
          c0 = __builtin_amdgcn_mfma_f32_32x32x16_bf16(aH[f], bH[g], c0, 0,0,0); \
          c0 = __builtin_amdgcn_mfma_f32_32x32x16_bf16(aH[f], bL[g], c0, 0,0,0); \
          c0 = __builtin_amdgcn_mfma_f32_32x32x16_bf16(aL[f], bH[g], c0, 0,0,0); \
          acc[f][g] = c0;                                                     \
        } }                                                                   \
      __builtin_amdgcn_s_setprio(0); }

  #define SB0() __builtin_amdgcn_sched_barrier(0)

  STAGE(0, 0)
  asm volatile("s_waitcnt vmcnt(0)" ::: "memory");
  __builtin_amdgcn_s_barrier();
  SB0();

  for (int t = 0; t < NT; t++){
    int buf = t & 1;
    if (t+1 < NT){
      STAGE(buf^1, t+1)
      asm volatile("s_waitcnt vmcnt(8)" ::: "memory");  // tile-t's 8 loads landed
    } else {
      asm volatile("s_waitcnt vmcnt(0)" ::: "memory");
    }
    __builtin_amdgcn_s_barrier();
    SB0();
    KSTEP(buf, rs0)
    KSTEP(buf, rs1)
    SB0();
    __builtin_amdgcn_s_barrier();   // all reads of buf done -> next STAGE may overwrite
    SB0();
  }

  #undef STAGE
  #undef KSTEP
  #undef SB0

  #pragma unroll
  for (int f = 0; f < 4; f++){
    int gr0 = bx*256 + wm + f*32;
    #pragma unroll
    for (int g = 0; g < 2; g++){
      int gc = by*256 + wn + g*32 + l31;
      #pragma unroll
      for (int i = 0; i < 16; i++){
        int r = (i & 3) + 8*(i >> 2) + 4*khg;
        Cb[(size_t)(gr0 + r) * 1024 + gc] = acc[f][g][i];
      }
    }
  }
}

// ---------- reduce split-K partials + scale + split to u16 [hi|lo] ----------
__global__ __launch_bounds__(256) void k_reduce_split(const float* __restrict__ P,
                                                      u16* __restrict__ Ws){
  int i = blockIdx.x*256 + threadIdx.x;
  int rg = i >> 8;                 // zb*1024 + d
  int c  = (i & 255) * 4;
  f32x4 a = *(const f32x4*)(P + (size_t)rg*1024 + c);
  f32x4 b = *(const f32x4*)(P + ((size_t)rg + 8192)*1024 + c);
  us4 h, l;
  #pragma unroll
  for (int j = 0; j < 4; j++){
    float x = (a[j] + b[j]) * 0.03125f;
    u16 hh = f2bf(x);
    h[j] = hh;
    l[j] = f2bf(x - bf2f(hh));
  }
  int zb = rg >> 10, d = rg & 1023;
  u16* Wb = Ws + (size_t)zb * ((size_t)DIM * 2*DIM);
  *(us4*)(Wb + (size_t)d*2048 + c)        = h;
  *(us4*)(Wb + (size_t)d*2048 + 1024 + c) = l;
}

// ---------- legacy 128x128 2-barrier GEMM (fallback tiers, verified R10) ----------
template<int KROW, int SPLITK, int SPLITOUT, int NOUT, int TX, int TY>
__global__ __launch_bounds__(256,4) void k_gemmS(const u16* __restrict__ A,
                                                 const u16* __restrict__ B,
                                                 void* __restrict__ Cout,
                                                 size_t aStride, size_t bStride, size_t cStride){
  constexpr int LA = 2*KROW;
  constexpr int ITER = (SPLITK ? 1024 : KROW) / 32;
  __shared__ __align__(16) u16 lds[4][128*32];

  int xcd = blockIdx.x & 7;
  int idx = blockIdx.x >> 3;
  int nPerX = gridDim.x >> 3;
  int gid = xcd * nPerX + idx;
  constexpr int TPZ = TX*TY;
  int z  = gid / TPZ;
  int rm = gid % TPZ;
  int bx = rm % TX;
  int by = rm / TX;
  int zb = SPLITK ? (z & 7) : z;
  int kh = SPLITK ? (z >> 3) : 0;

  const u16* Ab = A + (size_t)zb * aStride + (size_t)kh * 1024;
  const u16* Bb = B + (size_t)zb * bStride + (size_t)kh * 1024;

  int t = threadIdx.x, lane = t & 63, w = t >> 6;
  int wm = (w & 1) * 64, wn = (w >> 1) * 64;
  int fr = lane & 15;
  int srow    = lane >> 2;
  int srcSlot = ((lane & 3) ^ ((lane >> 3) & 3)) * 8;

  const u16* aBase = Ab + ((size_t)bx*128) * LA + srcSlot;
  const u16* bBase = Bb + ((size_t)by*128) * LA + srcSlot;
  int rdSlot = (((lane >> 4) ^ ((fr >> 1) & 3))) * 8;

  f32x4 acc[4][4] = {};

  for (int ti = 0; ti < ITER; ti++){
    size_t kof = (size_t)ti * 32;
    #pragma unroll
    for (int o = 0; o < 2; o++){
      int c = w*2 + o;
      size_t ro = (size_t)(c*16 + srow) * LA + kof;
      const u16* ga = aBase + ro;
      const u16* gb = bBase + ro;
      int le = c * 512;
      gload16(ga,        &lds[0][le]);
      gload16(ga + KROW, &lds[1][le]);
      gload16(gb,        &lds[2][le]);
      gload16(gb + KROW, &lds[3][le]);
    }
    __syncthreads();

    short8 fah[4], fal[4], fbh[4], fbl[4];
    #pragma unroll
    for (int mi = 0; mi < 4; mi++){
      fah[mi] = *(const short8*)&lds[0][(wm + mi*16 + fr)*32 + rdSlot];
      fal[mi] = *(const short8*)&lds[1][(wm + mi*16 + fr)*32 + rdSlot];
      fbh[mi] = *(const short8*)&lds[2][(wn + mi*16 + fr)*32 + rdSlot];
      fbl[mi] = *(const short8*)&lds[3][(wn + mi*16 + fr)*32 + rdSlot];
    }
    #pragma unroll
    for (int mi = 0; mi < 4; mi++){
      #pragma unroll
      for (int ni = 0; ni < 4; ni++){
        acc[mi][ni] = __builtin_amdgcn_mfma_f32_16x16x32_bf16(fah[mi], fbh[ni], acc[mi][ni], 0,0,0);
        acc[mi][ni] = __builtin_amdgcn_mfma_f32_16x16x32_bf16(fah[mi], fbl[ni], acc[mi][ni], 0,0,0);
        acc[mi][ni] = __builtin_amdgcn_mfma_f32_16x16x32_bf16(fal[mi], fbh[ni], acc[mi][ni], 0,0,0);
      }
    }
    __syncthreads();
  }

  int cr = (lane >> 4) * 4, cc = lane & 15;
  if (SPLITOUT){
    u16* Cb = (u16*)Cout + (size_t)z * cStride;
    const float scale = 0.03125f;
    #pragma unroll
    for (int mi = 0; mi < 4; mi++){
      int gr = bx*128 + wm + mi*16 + cr;
      #pragma unroll
      for (int ni = 0; ni < 4; ni++){
        int gc = by*128 + wn + ni*16 + cc;
        #pragma unroll
        for (int rr = 0; rr < 4; rr++){
          float x = acc[mi][ni][rr] * scale;
          u16 h = f2bf(x);
          u16 l = f2bf(x - bf2f(h));
          size_t off = (size_t)(gr + rr) * (2*NOUT) + gc;
          Cb[off]        = h;
          Cb[off + NOUT] = l;
        }
      }
    }
  } else {
    float* Cb = (float*)Cout + (size_t)z * cStride;
    #pragma unroll
    for (int mi = 0; mi < 4; mi++){
      int gr = bx*128 + wm + mi*16 + cr;
      #pragma unroll
      for (int ni = 0; ni < 4; ni++){
        int gc = by*128 + wn + ni*16 + cc;
        #pragma unroll
        for (int rr = 0; rr < 4; rr++){
          Cb[(size_t)(gr + rr) * NOUT + gc] = acc[mi][ni][rr];
        }
      }
    }
  }
}

// ---------- row softmax over D=1024, in place on d_out ----------
__global__ __launch_bounds__(256) void k_softmax(float* __restrict__ O){
  float* p = O + (size_t)blockIdx.x * DIM;
  int t = threadIdx.x;
  int lane = t & 63, wave = t >> 6;
  f32x4 v = *(f32x4*)(p + t*4);
  float m = fmaxf(fmaxf(v[0], v[1]), fmaxf(v[2], v[3]));
  #pragma unroll
  for (int o = 32; o > 0; o >>= 1) m = fmaxf(m, __shfl_xor(m, o));
  __shared__ float rmax[4], rsum[4];
  if (lane == 0) rmax[wave] = m;
  __syncthreads();
  m = fmaxf(fmaxf(rmax[0], rmax[1]), fmaxf(rmax[2], rmax[3]));
  float e0 = expf(v[0]-m), e1 = expf(v[1]-m), e2 = expf(v[2]-m), e3 = expf(v[3]-m);
  float s = e0 + e1 + e2 + e3;
  #pragma unroll
  for (int o = 32; o > 0; o >>= 1) s += __shfl_xor(s, o);
  if (lane == 0) rsum[wave] = s;
  __syncthreads();
  s = rsum[0] + rsum[1] + rsum[2] + rsum[3];
  float inv = 1.0f / s;
  f32x4 rv = { e0*inv, e1*inv, e2*inv, e3*inv };
  *(f32x4*)(p + t*4) = rv;
}

extern "C" void kernel_launch(void* const* d_in, const int* in_sizes, int n_in,
                              void* d_out, int out_size, void* d_ws, size_t ws_size,
                              hipStream_t stream){
  const float* Q = (const float*)d_in[0];
  const float* K = (const float*)d_in[1];
  const float* V = (const float*)d_in[2];
  float* Out = (float*)d_out;
  u16* w = (u16*)d_ws;

  const size_t QsB = (size_t)SEQ * (2*DIM);
  const size_t KtB = (size_t)DIM * (2*SEQ);
  const size_t VtB = KtB;
  const size_t WsB = (size_t)DIM * (2*DIM);

  dim3 blk(256);
  dim3 cgrid(SEQ/64, DIM/64, 16);

  const size_t base2 = 8 * (KtB + VtB + WsB) * sizeof(u16);          // ~167.8 MB
  const size_t needA = base2 + (size_t)16*1024*1024*sizeof(float);   // ~234.9 MB
  const size_t needB = base2;

  if (ws_size >= needA){
    u16* Kt = w;
    u16* Vt = Kt + 8*KtB;
    u16* Ws = Vt + 8*VtB;
    float* Part = (float*)(Ws + 8*WsB);
    u16* Qs = w;                         // reuses Kt/Vt region after GEMM-A (stream-ordered)
    k_convert_kv<<<cgrid, blk, 0, stream>>>(K, V, Kt, Vt);
    // GEMM-A (32x32 mfma3, split-K x2): Part[z=kh*8+zb] = Vt_zb . Kt_zb^T |_khalf
    k32<SEQ, 1, 4, 4><<<dim3(256), dim3(512), 0, stream>>>(
        Vt, Kt, Part, VtB, KtB, (size_t)1024*1024);
    k_reduce_split<<<dim3(8192), blk, 0, stream>>>(Part, Ws);
    k_split<<<dim3(2048), blk, 0, stream>>>(Q, Qs, 8*SEQ*(DIM/4));
    // GEMM-B (32x32 mfma3): Out = Qs . Ws^T
    k32<DIM, 0, 8, 4><<<dim3(256), dim3(512), 0, stream>>>(
        Qs, Ws, Out, QsB, WsB, (size_t)SEQ*DIM);
  } else if (ws_size >= needB){
    u16* Kt = w;
    u16* Vt = Kt + 8*KtB;
    u16* Ws = Vt + 8*VtB;
    u16* Qs = w;
    k_convert_kv<<<cgrid, blk, 0, stream>>>(K, V, Kt, Vt);
    k_gemmS<SEQ, 0, 1, DIM, 8, 8><<<dim3(512), blk, 0, stream>>>(
        Vt, Kt, Ws, VtB, KtB, WsB);
    k_split<<<dim3(2048), blk, 0, stream>>>(Q, Qs, 8*SEQ*(DIM/4));
    k_gemmS<DIM, 0, 0, DIM, 16, 8><<<dim3(1024), blk, 0, stream>>>(
        Qs, Ws, Out, QsB, WsB, (size_t)SEQ*DIM);
  } else {
    // per-batch fallback
    u16* Qs = w;
    u16* Kt = Qs + QsB;
    u16* Vt = Kt + KtB;
    u16* Ws = Vt + VtB;
    for (int b = 0; b < BATCH; b++){
      const size_t inOff = (size_t)b * SEQ * DIM;
      k_split<<<dim3(1024), blk, 0, stream>>>(Q + inOff, Qs, SEQ*(DIM/4));
      k_convert_kv<<<dim3(SEQ/64, DIM/64, 1), blk, 0, stream>>>(K + inOff, K + inOff, Kt, Kt);
      k_convert_kv<<<dim3(SEQ/64, DIM/64, 1), blk, 0, stream>>>(V + inOff, V + inOff, Vt, Vt);
      k_gemmS<SEQ, 0, 1, DIM, 8, 8><<<dim3(64), blk, 0, stream>>>(
          Vt, Kt, Ws, VtB, KtB, WsB);
      k_gemmS<DIM, 0, 0, DIM, 16, 8><<<dim3(128), blk, 0, stream>>>(
          Qs, Ws, Out + inOff, QsB, WsB, (size_t)SEQ*DIM);
    }
  }
  k_softmax<<<dim3(BATCH*SEQ), blk, 0, stream>>>(Out);
}

// Round 14
// 267.540 us; speedup vs baseline: 1.1305x; 1.1305x over previous
//
#include <hip/hip_runtime.h>
#include <hip/hip_bf16.h>
#include <stdint.h>

#define BATCH 8
#define SEQ   2048
#define DIM   1024

typedef unsigned short u16;
typedef __attribute__((ext_vector_type(8))) short short8;
typedef __attribute__((ext_vector_type(4))) float f32x4;
typedef __attribute__((ext_vector_type(4))) unsigned short us4;

__device__ __forceinline__ u16 f2bf(float x){
  union { float f; uint32_t u; } c; c.f = x;
  uint32_t u = c.u;
  uint32_t r = u + 0x7fffu + ((u >> 16) & 1u);
  return (u16)(r >> 16);
}
__device__ __forceinline__ float bf2f(u16 s){
  union { uint32_t u; float f; } c; c.u = ((uint32_t)s) << 16;
  return c.f;
}

__device__ __forceinline__ void gload16(const void* g, void* l){
  __builtin_amdgcn_global_load_lds(
      (const __attribute__((address_space(1))) void*)g,
      (__attribute__((address_space(3))) void*)l, 16, 0, 0);
}

// ---------- split fp32 [R][1024] -> u16 [R][2048] rows packed [hi|lo] ----------
__global__ __launch_bounds__(256) void k_split(const float* __restrict__ src,
                                               u16* __restrict__ dst, int nchunk){
  for (int i = blockIdx.x*blockDim.x + threadIdx.x; i < nchunk; i += gridDim.x*blockDim.x){
    int r = i >> 8;
    int c = (i & 255) << 2;
    f32x4 v = *(const f32x4*)(src + (size_t)r*DIM + c);
    us4 h, l;
    #pragma unroll
    for (int j = 0; j < 4; j++){
      u16 hh = f2bf(v[j]);
      h[j] = hh;
      l[j] = f2bf(v[j] - bf2f(hh));
    }
    u16* d = dst + (size_t)r*(2*DIM) + c;
    *(us4*)d         = h;
    *(us4*)(d + DIM) = l;
  }
}

// ---------- transpose + split (K and V in one launch): z<8 -> K->Kt, z>=8 -> V->Vt ----------
__global__ __launch_bounds__(256) void k_convert_kv(const float* __restrict__ K,
                                                    const float* __restrict__ V,
                                                    u16* __restrict__ Kt,
                                                    u16* __restrict__ Vt){
  __shared__ float tile[64][65];
  int z = blockIdx.z;
  const float* Src = (z < 8 ? K : V);
  u16* Dst = (z < 8 ? Kt : Vt);
  int zb = z & 7;
  const float* Vb = Src + (size_t)zb * SEQ * DIM;
  u16* Vtb = Dst + (size_t)zb * DIM * (2*SEQ);
  int s0 = blockIdx.x * 64, d0 = blockIdx.y * 64;
  int t = threadIdx.x;
  int rs = t >> 4;
  int cd = (t & 15) * 4;
  #pragma unroll
  for (int i = 0; i < 4; i++){
    int s = rs + i*16;
    f32x4 v = *(const f32x4*)(Vb + (size_t)(s0 + s)*DIM + d0 + cd);
    tile[s][cd+0] = v[0]; tile[s][cd+1] = v[1];
    tile[s][cd+2] = v[2]; tile[s][cd+3] = v[3];
  }
  __syncthreads();
  int dl = t >> 4;
  int sl = (t & 15) * 4;
  #pragma unroll
  for (int i = 0; i < 4; i++){
    int d = dl + i*16;
    us4 h, l;
    #pragma unroll
    for (int j = 0; j < 4; j++){
      float x = tile[sl+j][d];
      u16 hh = f2bf(x);
      h[j] = hh;
      l[j] = f2bf(x - bf2f(hh));
    }
    size_t off = (size_t)(d0 + d) * (2*SEQ) + s0 + sl;
    *(us4*)(Vtb + off)       = h;
    *(us4*)(Vtb + off + SEQ) = l;
  }
}

// ---------- 256x256 8-wave GEMM, hi/lo mfma3, quarter-interleaved pipeline ----------
// LDS [2 buf][Ah,Al,Bh,Bl][256 rows x 32] = 128 KB; rows quarter-permuted:
//  A: LDS j<128 = quarter a0 = global rows {0-63,128-191}; j>=128 = a1 = {64-127,192-255}
//  B: LDS j<128 = b0 = {wn+[0,32) for wn in 0,64,128,192}; j>=128 = b1 = +32
// Per K-tile t (4 phases): stage quarters [a0,b0,b1,a1] of t+1 one per phase,
// boundary vmcnt(4) certifies {a0,b0}(t), mid-tile vmcnt(2) certifies {b1,a1}(t).
// 2 barriers/tile, no mid-loop drain to 0. SPLITK: z=(kh<<3)|zb contracts K-half kh.
template<int KROW, int SPLITK, int TX, int TY>
__global__ __launch_bounds__(512,1) void k8n(const u16* __restrict__ A,
                                             const u16* __restrict__ B,
                                             float* __restrict__ C,
                                             size_t aStride, size_t bStride, size_t cStride){
  constexpr int LA = 2*KROW;
  constexpr int NT = (SPLITK ? 1024 : KROW) / 32;
  __shared__ __align__(16) u16 lds[2][4][256*32];

  int xcd = blockIdx.x & 7;
  int idx = blockIdx.x >> 3;
  int nPerX = gridDim.x >> 3;
  int gid = xcd * nPerX + idx;
  constexpr int TPZ = TX*TY;
  int z  = gid / TPZ;
  int rm = gid % TPZ;
  int bx = rm % TX;
  int by = rm / TX;
  int zb = SPLITK ? (z & 7) : z;
  int kh = SPLITK ? (z >> 3) : 0;

  const u16* Ab = A + (size_t)zb * aStride + (size_t)kh * 1024;
  const u16* Bb = B + (size_t)zb * bStride + (size_t)kh * 1024;
  float* Cb = C + (size_t)z * cStride;

  int t0 = threadIdx.x, lane = t0 & 63, wv = t0 >> 6;
  int wm = (wv >> 2) * 128, wn = (wv & 3) * 64;
  int fr = lane & 15;
  int rdSlot  = ((lane >> 4) ^ ((fr >> 1) & 3)) * 8;
  int srcSlot = ((lane & 3) ^ ((lane >> 3) & 3)) * 8;

  // staging: thread covers quarter-local LDS row jj, global row gA/gB (+64/+32 for 2nd quarter)
  int jj = wv*16 + (lane >> 2);
  int gA = (jj & 63) + (jj >> 6) * 128;
  int gB = (jj & 31) + (jj >> 5) * 64;

  const u16* aB = Ab + (size_t)bx*256*LA + srcSlot;
  const u16* bB = Bb + (size_t)by*256*LA + srcSlot;
  int ldst = wv*512;

  f32x4 acc[8][4] = {};
  short8 aH[4], aL[4], b0H[2], b0L[2], b1H[2], b1L[2];

  #define STAGE_QA(buf, t32, p) {                                             \
    size_t ko = (size_t)(t32)*32 + (size_t)(gA + (p)*64)*LA;                  \
    gload16(aB + ko,        &lds[buf][0][(p)*4096 + ldst]);                   \
    gload16(aB + ko + KROW, &lds[buf][1][(p)*4096 + ldst]); }
  #define STAGE_QB(buf, t32, p) {                                             \
    size_t ko = (size_t)(t32)*32 + (size_t)(gB + (p)*32)*LA;                  \
    gload16(bB + ko,        &lds[buf][2][(p)*4096 + ldst]);                   \
    gload16(bB + ko + KROW, &lds[buf][3][(p)*4096 + ldst]); }

  #define LD_A(buf, h) { _Pragma("unroll") for (int q = 0; q < 4; q++){       \
      int g = wm + ((h)*4+q)*16 + fr;                                         \
      int ja = (g & 63) + ((g >> 7) & 1)*64 + ((g >> 6) & 1)*128;             \
      aH[q] = *(const short8*)&lds[buf][0][ja*32 + rdSlot];                   \
      aL[q] = *(const short8*)&lds[buf][1][ja*32 + rdSlot]; } }
  #define LD_B(buf, gb, BH, BL) { _Pragma("unroll") for (int n = 0; n < 2; n++){ \
      int g = wn + ((gb)*2+n)*16 + fr;                                        \
      int jb = (g & 31) + ((g >> 6) & 3)*32 + ((g >> 5) & 1)*128;             \
      BH[n] = *(const short8*)&lds[buf][2][jb*32 + rdSlot];                   \
      BL[n] = *(const short8*)&lds[buf][3][jb*32 + rdSlot]; } }

  #define MM8(h, BH, BL, nb) { _Pragma("unroll") for (int q = 0; q < 4; q++){ \
      _Pragma("unroll") for (int n = 0; n < 2; n++){                          \
        f32x4 c0 = acc[(h)*4+q][(nb)+n];                                      \
        c0 = __builtin_amdgcn_mfma_f32_16x16x32_bf16(aH[q], BH[n], c0, 0,0,0);\
        c0 = __builtin_amdgcn_mfma_f32_16x16x32_bf16(aH[q], BL[n], c0, 0,0,0);\
        c0 = __builtin_amdgcn_mfma_f32_16x16x32_bf16(aL[q], BH[n], c0, 0,0,0);\
        acc[(h)*4+q][(nb)+n] = c0; } } }

  #define SB0() __builtin_amdgcn_sched_barrier(0)

  // prologue: stage tile 0 quarters in ledger order [a0,b0,b1,a1] -> 8 loads
  STAGE_QA(0, 0, 0) STAGE_QB(0, 0, 0) STAGE_QB(0, 0, 1) STAGE_QA(0, 0, 1)

  for (int t = 0; t < NT; t++){
    int buf = t & 1, sb = buf ^ 1;
    bool st = (t + 1 < NT);
    // boundary: certify {a0,b0}(t); 4 loads of t may remain in flight
    asm volatile("s_waitcnt vmcnt(4)" ::: "memory");
    SB0();
    __builtin_amdgcn_s_barrier();
    SB0();
    // P0: reads a0+b0 frags, stage a0(t+1), MFMA X0 = A0-3 x B0-1
    LD_A(buf, 0)
    LD_B(buf, 0, b0H, b0L)
    if (st) STAGE_QA(sb, t+1, 0)
    __builtin_amdgcn_s_setprio(1);
    MM8(0, b0H, b0L, 0)
    __builtin_amdgcn_s_setprio(0);
    // mid-tile: certify {b1,a1}(t); a0(t+1) may remain in flight
    if (st){ asm volatile("s_waitcnt vmcnt(2)" ::: "memory"); }
    else   { asm volatile("s_waitcnt vmcnt(0)" ::: "memory"); }
    SB0();
    __builtin_amdgcn_s_barrier();
    SB0();
    // P1: reads b1 frags, stage b0(t+1), MFMA X1 = A0-3 x B2-3
    LD_B(buf, 1, b1H, b1L)
    if (st) STAGE_QB(sb, t+1, 0)
    __builtin_amdgcn_s_setprio(1);
    MM8(0, b1H, b1L, 2)
    __builtin_amdgcn_s_setprio(0);
    // P2: reads a1 frags, stage b1(t+1), MFMA X2 = A4-7 x B2-3
    LD_A(buf, 1)
    if (st) STAGE_QB(sb, t+1, 1)
    __builtin_amdgcn_s_setprio(1);
    MM8(1, b1H, b1L, 2)
    __builtin_amdgcn_s_setprio(0);
    // P3: no reads (B0-1 held in regs), stage a1(t+1), MFMA X3 = A4-7 x B0-1
    if (st) STAGE_QA(sb, t+1, 1)
    __builtin_amdgcn_s_setprio(1);
    MM8(1, b0H, b0L, 0)
    __builtin_amdgcn_s_setprio(0);
  }

  #undef STAGE_QA
  #undef STAGE_QB
  #undef LD_A
  #undef LD_B
  #undef MM8
  #undef SB0

  int cr = (lane >> 4) * 4;
  #pragma unroll
  for (int mi = 0; mi < 8; mi++){
    int gr = bx*256 + wm + mi*16 + cr;
    #pragma unroll
    for (int ni = 0; ni < 4; ni++){
      int gc = by*256 + wn + ni*16 + fr;
      #pragma unroll
      for (int e = 0; e < 4; e++)
        Cb[(size_t)(gr + e) * 1024 + gc] = acc[mi][ni][e];
    }
  }
}

// ---------- reduce split-K partials + scale + split to u16 [hi|lo] ----------
__global__ __launch_bounds__(256) void k_reduce_split(const float* __restrict__ P,
                                                      u16* __restrict__ Ws){
  int i = blockIdx.x*256 + threadIdx.x;
  int rg = i >> 8;                 // zb*1024 + d
  int c  = (i & 255) * 4;
  f32x4 a = *(const f32x4*)(P + (size_t)rg*1024 + c);
  f32x4 b = *(const f32x4*)(P + ((size_t)rg + 8192)*1024 + c);
  us4 h, l;
  #pragma unroll
  for (int j = 0; j < 4; j++){
    float x = (a[j] + b[j]) * 0.03125f;
    u16 hh = f2bf(x);
    h[j] = hh;
    l[j] = f2bf(x - bf2f(hh));
  }
  int zb = rg >> 10, d = rg & 1023;
  u16* Wb = Ws + (size_t)zb * ((size_t)DIM * 2*DIM);
  *(us4*)(Wb + (size_t)d*2048 + c)        = h;
  *(us4*)(Wb + (size_t)d*2048 + 1024 + c) = l;
}

// ---------- legacy 128x128 2-barrier GEMM (fallback tiers, verified R10) ----------
template<int KROW, int SPLITK, int SPLITOUT, int NOUT, int TX, int TY>
__global__ __launch_bounds__(256,4) void k_gemmS(const u16* __restrict__ A,
                                                 const u16* __restrict__ B,
                                                 void* __restrict__ Cout,
                                                 size_t aStride, size_t bStride, size_t cStride){
  constexpr int LA = 2*KROW;
  constexpr int ITER = (SPLITK ? 1024 : KROW) / 32;
  __shared__ __align__(16) u16 lds[4][128*32];

  int xcd = blockIdx.x & 7;
  int idx = blockIdx.x >> 3;
  int nPerX = gridDim.x >> 3;
  int gid = xcd * nPerX + idx;
  constexpr int TPZ = TX*TY;
  int z  = gid / TPZ;
  int rm = gid % TPZ;
  int bx = rm % TX;
  int by = rm / TX;
  int zb = SPLITK ? (z & 7) : z;
  int kh = SPLITK ? (z >> 3) : 0;

  const u16* Ab = A + (size_t)zb * aStride + (size_t)kh * 1024;
  const u16* Bb = B + (size_t)zb * bStride + (size_t)kh * 1024;

  int t = threadIdx.x, lane = t & 63, w = t >> 6;
  int wm = (w & 1) * 64, wn = (w >> 1) * 64;
  int fr = lane & 15;
  int srow    = lane >> 2;
  int srcSlot = ((lane & 3) ^ ((lane >> 3) & 3)) * 8;

  const u16* aBase = Ab + ((size_t)bx*128) * LA + srcSlot;
  const u16* bBase = Bb + ((size_t)by*128) * LA + srcSlot;
  int rdSlot = (((lane >> 4) ^ ((fr >> 1) & 3))) * 8;

  f32x4 acc[4][4] = {};

  for (int ti = 0; ti < ITER; ti++){
    size_t kof = (size_t)ti * 32;
    #pragma unroll
    for (int o = 0; o < 2; o++){
      int c = w*2 + o;
      size_t ro = (size_t)(c*16 + srow) * LA + kof;
      const u16* ga = aBase + ro;
      const u16* gb = bBase + ro;
      int le = c * 512;
      gload16(ga,        &lds[0][le]);
      gload16(ga + KROW, &lds[1][le]);
      gload16(gb,        &lds[2][le]);
      gload16(gb + KROW, &lds[3][le]);
    }
    __syncthreads();

    short8 fah[4], fal[4], fbh[4], fbl[4];
    #pragma unroll
    for (int mi = 0; mi < 4; mi++){
      fah[mi] = *(const short8*)&lds[0][(wm + mi*16 + fr)*32 + rdSlot];
      fal[mi] = *(const short8*)&lds[1][(wm + mi*16 + fr)*32 + rdSlot];
      fbh[mi] = *(const short8*)&lds[2][(wn + mi*16 + fr)*32 + rdSlot];
      fbl[mi] = *(const short8*)&lds[3][(wn + mi*16 + fr)*32 + rdSlot];
    }
    #pragma unroll
    for (int mi = 0; mi < 4; mi++){
      #pragma unroll
      for (int ni = 0; ni < 4; ni++){
        acc[mi][ni] = __builtin_amdgcn_mfma_f32_16x16x32_bf16(fah[mi], fbh[ni], acc[mi][ni], 0,0,0);
        acc[mi][ni] = __builtin_amdgcn_mfma_f32_16x16x32_bf16(fah[mi], fbl[ni], acc[mi][ni], 0,0,0);
        acc[mi][ni] = __builtin_amdgcn_mfma_f32_16x16x32_bf16(fal[mi], fbh[ni], acc[mi][ni], 0,0,0);
      }
    }
    __syncthreads();
  }

  int cr = (lane >> 4) * 4, cc = lane & 15;
  if (SPLITOUT){
    u16* Cb = (u16*)Cout + (size_t)z * cStride;
    const float scale = 0.03125f;
    #pragma unroll
    for (int mi = 0; mi < 4; mi++){
      int gr = bx*128 + wm + mi*16 + cr;
      #pragma unroll
      for (int ni = 0; ni < 4; ni++){
        int gc = by*128 + wn + ni*16 + cc;
        #pragma unroll
        for (int rr = 0; rr < 4; rr++){
          float x = acc[mi][ni][rr] * scale;
          u16 h = f2bf(x);
          u16 l = f2bf(x - bf2f(h));
          size_t off = (size_t)(gr + rr) * (2*NOUT) + gc;
          Cb[off]        = h;
          Cb[off + NOUT] = l;
        }
      }
    }
  } else {
    float* Cb = (float*)Cout + (size_t)z * cStride;
    #pragma unroll
    for (int mi = 0; mi < 4; mi++){
      int gr = bx*128 + wm + mi*16 + cr;
      #pragma unroll
      for (int ni = 0; ni < 4; ni++){
        int gc = by*128 + wn + ni*16 + cc;
        #pragma unroll
        for (int rr = 0; rr < 4; rr++){
          Cb[(size_t)(gr + rr) * NOUT + gc] = acc[mi][ni][rr];
        }
      }
    }
  }
}

// ---------- row softmax over D=1024, in place on d_out ----------
__global__ __launch_bounds__(256) void k_softmax(float* __restrict__ O){
  float* p = O + (size_t)blockIdx.x * DIM;
  int t = threadIdx.x;
  int lane = t & 63, wave = t >> 6;
  f32x4 v = *(f32x4*)(p + t*4);
  float m = fmaxf(fmaxf(v[0], v[1]), fmaxf(v[2], v[3]));
  #pragma unroll
  for (int o = 32; o > 0; o >>= 1) m = fmaxf(m, __shfl_xor(m, o));
  __shared__ float rmax[4], rsum[4];
  if (lane == 0) rmax[wave] = m;
  __syncthreads();
  m = fmaxf(fmaxf(rmax[0], rmax[1]), fmaxf(rmax[2], rmax[3]));
  float e0 = expf(v[0]-m), e1 = expf(v[1]-m), e2 = expf(v[2]-m), e3 = expf(v[3]-m);
  float s = e0 + e1 + e2 + e3;
  #pragma unroll
  for (int o = 32; o > 0; o >>= 1) s += __shfl_xor(s, o);
  if (lane == 0) rsum[wave] = s;
  __syncthreads();
  s = rsum[0] + rsum[1] + rsum[2] + rsum[3];
  float inv = 1.0f / s;
  f32x4 rv = { e0*inv, e1*inv, e2*inv, e3*inv };
  *(f32x4*)(p + t*4) = rv;
}

extern "C" void kernel_launch(void* const* d_in, const int* in_sizes, int n_in,
                              void* d_out, int out_size, void* d_ws, size_t ws_size,
                              hipStream_t stream){
  const float* Q = (const float*)d_in[0];
  const float* K = (const float*)d_in[1];
  const float* V = (const float*)d_in[2];
  float* Out = (float*)d_out;
  u16* w = (u16*)d_ws;

  const size_t QsB = (size_t)SEQ * (2*DIM);
  const size_t KtB = (size_t)DIM * (2*SEQ);
  const size_t VtB = KtB;
  const size_t WsB = (size_t)DIM * (2*DIM);

  dim3 blk(256);
  dim3 cgrid(SEQ/64, DIM/64, 16);

  const size_t base2 = 8 * (KtB + VtB + WsB) * sizeof(u16);          // ~167.8 MB
  const size_t needA = base2 + (size_t)16*1024*1024*sizeof(float);   // ~234.9 MB
  const size_t needB = base2;

  if (ws_size >= needA){
    u16* Kt = w;
    u16* Vt = Kt + 8*KtB;
    u16* Ws = Vt + 8*VtB;
    float* Part = (float*)(Ws + 8*WsB);
    u16* Qs = w;                         // reuses Kt/Vt region after GEMM-A (stream-ordered)
    k_convert_kv<<<cgrid, blk, 0, stream>>>(K, V, Kt, Vt);
    // GEMM-A (quarter-pipelined, split-K x2): Part[z=kh*8+zb] = Vt_zb . Kt_zb^T |_khalf
    k8n<SEQ, 1, 4, 4><<<dim3(256), dim3(512), 0, stream>>>(
        Vt, Kt, Part, VtB, KtB, (size_t)1024*1024);
    k_reduce_split<<<dim3(8192), blk, 0, stream>>>(Part, Ws);
    k_split<<<dim3(2048), blk, 0, stream>>>(Q, Qs, 8*SEQ*(DIM/4));
    // GEMM-B (quarter-pipelined): Out = Qs . Ws^T
    k8n<DIM, 0, 8, 4><<<dim3(256), dim3(512), 0, stream>>>(
        Qs, Ws, Out, QsB, WsB, (size_t)SEQ*DIM);
  } else if (ws_size >= needB){
    u16* Kt = w;
    u16* Vt = Kt + 8*KtB;
    u16* Ws = Vt + 8*VtB;
    u16* Qs = w;
    k_convert_kv<<<cgrid, blk, 0, stream>>>(K, V, Kt, Vt);
    k_gemmS<SEQ, 0, 1, DIM, 8, 8><<<dim3(512), blk, 0, stream>>>(
        Vt, Kt, Ws, VtB, KtB, WsB);
    k_split<<<dim3(2048), blk, 0, stream>>>(Q, Qs, 8*SEQ*(DIM/4));
    k8n<DIM, 0, 8, 4><<<dim3(256), dim3(512), 0, stream>>>(
        Qs, Ws, Out, QsB, WsB, (size_t)SEQ*DIM);
  } else {
    // per-batch fallback
    u16* Qs = w;
    u16* Kt = Qs + QsB;
    u16* Vt = Kt + KtB;
    u16* Ws = Vt + VtB;
    for (int b = 0; b < BATCH; b++){
      const size_t inOff = (size_t)b * SEQ * DIM;
      k_split<<<dim3(1024), blk, 0, stream>>>(Q + inOff, Qs, SEQ*(DIM/4));
      k_convert_kv<<<dim3(SEQ/64, DIM/64, 1), blk, 0, stream>>>(K + inOff, K + inOff, Kt, Kt);
      k_convert_kv<<<dim3(SEQ/64, DIM/64, 1), blk, 0, stream>>>(V + inOff, V + inOff, Vt, Vt);
      k_gemmS<SEQ, 0, 1, DIM, 8, 8><<<dim3(64), blk, 0, stream>>>(
          Vt, Kt, Ws, VtB, KtB, WsB);
      k_gemmS<DIM, 0, 0, DIM, 16, 8><<<dim3(128), blk, 0, stream>>>(
          Qs, Ws, Out + inOff, QsB, WsB, (size_t)SEQ*DIM);
    }
  }
  k_softmax<<<dim3(BATCH*SEQ), blk, 0, stream>>>(Out);
}